// Round 1
// baseline (534.893 us; speedup 1.0000x reference)
//
#include <hip/hip_runtime.h>

typedef __bf16 bf16x8 __attribute__((ext_vector_type(8)));
typedef float f32x4 __attribute__((ext_vector_type(4)));
typedef unsigned int u32x4 __attribute__((ext_vector_type(4)));
typedef unsigned short u16x4 __attribute__((ext_vector_type(4)));

__device__ __forceinline__ unsigned short f2b(float f) {
  union { float f; unsigned int u; } a; a.f = f;
  unsigned int u = a.u;
  u += 0x7fffu + ((u >> 16) & 1u);   // round-to-nearest-even
  return (unsigned short)(u >> 16);
}

#define LDW 136  // padded LDS row stride in bf16 elems (+8 keeps 16B align, kills bank conflicts)

__global__ void prep_weights(const float* __restrict__ wa,
                             const float* __restrict__ wb,
                             unsigned short* __restrict__ owa,
                             unsigned short* __restrict__ owb) {
  int t = blockIdx.x * 256 + threadIdx.x;           // 0..32767
  if (t < 128 * 128) owa[t] = f2b(wa[t]);
  else               owb[t - 128 * 128] = f2b(wb[t - 128 * 128]);
}

// One block = one sample. 512 threads = 8 waves; wave w owns output column tile w (16 cols).
// Y = Wa * (M * Wb^T) + bias,  M = row-major reshape of x[n] to 128x128.
//
// Single 34.8 KB LDS buffer (was 69.6 KB): stage-1 results are kept packed-bf16 in
// registers across a barrier, then U^T overwrites Mlds in place. 160KB/34.8KB ->
// 4 blocks/CU = 32 waves/CU (was 2 blocks / 16 waves) for latency hiding.
__global__ __launch_bounds__(512, 8)
void krone_kernel(const float* __restrict__ x,
                  const unsigned short* __restrict__ wa,   // bf16 bits, [128][128]
                  const unsigned short* __restrict__ wb,   // bf16 bits, [128][128]
                  const float* __restrict__ bias,
                  float* __restrict__ out) {
  __shared__ unsigned short Mlds[128 * LDW];   // M, then (after barrier 2) U^T, row-major bf16

  const int tid  = threadIdx.x;
  const int lane = tid & 63;
  const int w    = tid >> 6;   // wave id == n-tile (0..7)
  const int quad = lane >> 4;  // 0..3
  const int l16  = lane & 15;

  // ---- stage M (fp32 -> bf16) into LDS, coalesced float4 loads ----
  const float* xrow = x + (size_t)blockIdx.x * 16384;
  #pragma unroll
  for (int i = 0; i < 8; ++i) {
    int idx = (i << 9) + tid;                     // float4 index 0..4095
    f32x4 v = *(const f32x4*)(xrow + (idx << 2));
    int r = idx >> 5;
    int c = (idx & 31) << 2;
    u16x4 h;
    h[0] = f2b(v[0]); h[1] = f2b(v[1]); h[2] = f2b(v[2]); h[3] = f2b(v[3]);
    *(u16x4*)&Mlds[r * LDW + c] = h;              // 8B write, ~conflict-free
  }

  // ---- hoist Wb B-fragments for this wave's n-tile (sample-invariant) ----
  // B[k][n] = Wb[n][k]; lane holds n=l16, k=quad*8+j -> contiguous row read.
  bf16x8 wbf[4];
  {
    const unsigned short* wbr = wb + (w * 16 + l16) * 128 + quad * 8;
    #pragma unroll
    for (int kk = 0; kk < 4; ++kk)
      wbf[kk] = __builtin_bit_cast(bf16x8, *(const u32x4*)(wbr + kk * 32));
  }

  __syncthreads();   // barrier 1: M fully staged

  // ---- stage 1: U = M * Wb^T for cols [16w,16w+16); keep packed results in regs ----
  u16x4 ur[8];   // statically indexed (full unroll) -> stays in VGPRs
  #pragma unroll
  for (int m = 0; m < 8; ++m) {
    f32x4 acc = {0.f, 0.f, 0.f, 0.f};
    const unsigned short* mr = &Mlds[(m * 16 + l16) * LDW + quad * 8];
    #pragma unroll
    for (int kk = 0; kk < 4; ++kk) {
      u32x4 ua = *(const u32x4*)(mr + kk * 32);
      acc = __builtin_amdgcn_mfma_f32_16x16x32_bf16(
              __builtin_bit_cast(bf16x8, ua), wbf[kk], acc, 0, 0, 0);
    }
    // C layout: acc[i] = U[m*16 + quad*4 + i][16w + l16]
    u16x4 h;
    h[0] = f2b(acc[0]); h[1] = f2b(acc[1]); h[2] = f2b(acc[2]); h[3] = f2b(acc[3]);
    ur[m] = h;
  }

  __syncthreads();   // barrier 2: all waves done READING M; safe to overwrite

  // ---- write U^T stripe into the SAME buffer (8B writes) ----
  #pragma unroll
  for (int m = 0; m < 8; ++m)
    *(u16x4*)&Mlds[(w * 16 + l16) * LDW + m * 16 + quad * 4] = ur[m];
  // No barrier: wave w reads back only U^T rows [16w,16w+16) which it wrote itself.

  // ---- stage 2: Y = Wa * U for cols [16w,16w+16); fused bias + store ----
  float* orow = out + (size_t)blockIdx.x * 16384;
  #pragma unroll
  for (int m = 0; m < 8; ++m) {
    f32x4 acc = {0.f, 0.f, 0.f, 0.f};
    const unsigned short* war = wa + (m * 16 + l16) * 128 + quad * 8;  // A = Wa rows (L1-hot)
    const unsigned short* utr = &Mlds[(w * 16 + l16) * LDW + quad * 8]; // B = U^T row n
    #pragma unroll
    for (int kk = 0; kk < 4; ++kk) {
      u32x4 ua = *(const u32x4*)(war + kk * 32);
      u32x4 ub = *(const u32x4*)(utr + kk * 32);
      acc = __builtin_amdgcn_mfma_f32_16x16x32_bf16(
              __builtin_bit_cast(bf16x8, ua),
              __builtin_bit_cast(bf16x8, ub), acc, 0, 0, 0);
    }
    int row0 = m * 16 + quad * 4;
    int col  = w * 16 + l16;
    #pragma unroll
    for (int i = 0; i < 4; ++i) {
      int r = row0 + i;
      orow[r * 128 + col] = acc[i] + bias[r * 128 + col];  // 64B-contiguous per 16 lanes
    }
  }
}

extern "C" void kernel_launch(void* const* d_in, const int* in_sizes, int n_in,
                              void* d_out, int out_size, void* d_ws, size_t ws_size,
                              hipStream_t stream) {
  const float* x  = (const float*)d_in[0];
  const float* wa = (const float*)d_in[1];
  const float* wb = (const float*)d_in[2];
  const float* bs = (const float*)d_in[3];
  float* out = (float*)d_out;

  unsigned short* wsa = (unsigned short*)d_ws;      // 32 KB bf16 Wa
  unsigned short* wsb = wsa + 128 * 128;            // 32 KB bf16 Wb

  int N = in_sizes[0] / 16384;                      // 4096

  prep_weights<<<128, 256, 0, stream>>>(wa, wb, wsa, wsb);
  krone_kernel<<<N, 512, 0, stream>>>(x, wsa, wsb, bs, out);
}

// Round 2
// 475.517 us; speedup vs baseline: 1.1249x; 1.1249x over previous
//
#include <hip/hip_runtime.h>

typedef __bf16 bf16x8 __attribute__((ext_vector_type(8)));
typedef float f32x4 __attribute__((ext_vector_type(4)));
typedef unsigned int u32x4 __attribute__((ext_vector_type(4)));
typedef unsigned short u16x4 __attribute__((ext_vector_type(4)));

__device__ __forceinline__ unsigned short f2b(float f) {
  union { float f; unsigned int u; } a; a.f = f;
  unsigned int u = a.u;
  u += 0x7fffu + ((u >> 16) & 1u);   // round-to-nearest-even
  return (unsigned short)(u >> 16);
}

#define LDW 136  // padded LDS row stride in bf16 elems (+8 keeps 16B align, kills bank conflicts)

// owa: Wa in MFMA B-fragment order [mp][kk][lane][8] so stage-2 weight reads are
//      contiguous 1KB wave-loads (was a 64-cache-line scatter per instruction).
// owb: Wb row-major bf16 (stage-1 hoist reads it only once per block).
__global__ void prep_weights(const float* __restrict__ wa,
                             const float* __restrict__ wb,
                             unsigned short* __restrict__ owa,
                             unsigned short* __restrict__ owb) {
  int t = blockIdx.x * 256 + threadIdx.x;           // 0..32767
  if (t < 16384) {
    int j    = t & 7;
    int lane = (t >> 3) & 63;
    int kk   = (t >> 9) & 3;
    int mp   = t >> 11;                              // 0..7
    int quad = lane >> 4, l16 = lane & 15;
    // B[k][n] = Wa^T[k][n] = Wa[n][k];  n = mp*16+l16 (Y row), k = kk*32 + quad*8 + j
    owa[t] = f2b(wa[(mp * 16 + l16) * 128 + kk * 32 + quad * 8 + j]);
  } else {
    int u = t - 16384;
    owb[u] = f2b(wb[u]);
  }
}

// One block = one sample. 512 threads = 8 waves; wave w owns output column tile w (16 cols).
// Y = Wa * (M * Wb^T) + bias,  M = row-major reshape of x[n] to 128x128.
// Stage 2 computes D = U^T-rows x Wa^T (operand swap): lane then holds 4 consecutive
// Y columns -> f32x4 stores + f32x4 bias loads, and the U^T A-fragment is invariant
// over the output-tile loop (hoisted: 4 LDS reads instead of 32).
__global__ __launch_bounds__(512, 4)
void krone_kernel(const float* __restrict__ x,
                  const unsigned short* __restrict__ waf,  // bf16 bits, fragment order [8][4][64][8]
                  const unsigned short* __restrict__ wb,   // bf16 bits, [128][128]
                  const float* __restrict__ bias,
                  float* __restrict__ out) {
  __shared__ unsigned short Mlds[128 * LDW];   // M, then (after barrier 2) U^T in place

  const int tid  = threadIdx.x;
  const int lane = tid & 63;
  const int w    = tid >> 6;   // wave id == n-tile (0..7)
  const int quad = lane >> 4;  // 0..3
  const int l16  = lane & 15;

  // ---- stage M (fp32 -> bf16) into LDS, coalesced float4 loads ----
  const float* xrow = x + (size_t)blockIdx.x * 16384;
  #pragma unroll
  for (int i = 0; i < 8; ++i) {
    int idx = (i << 9) + tid;                     // float4 index 0..4095
    f32x4 v = *(const f32x4*)(xrow + (idx << 2));
    int r = idx >> 5;
    int c = (idx & 31) << 2;
    u16x4 h;
    h[0] = f2b(v[0]); h[1] = f2b(v[1]); h[2] = f2b(v[2]); h[3] = f2b(v[3]);
    *(u16x4*)&Mlds[r * LDW + c] = h;              // 8B write, ~conflict-free
  }

  // ---- hoist Wb B-fragments for this wave's n-tile (sample-invariant) ----
  bf16x8 wbf[4];
  {
    const unsigned short* wbr = wb + (w * 16 + l16) * 128 + quad * 8;
    #pragma unroll
    for (int kk = 0; kk < 4; ++kk)
      wbf[kk] = __builtin_bit_cast(bf16x8, *(const u32x4*)(wbr + kk * 32));
  }

  __syncthreads();   // barrier 1: M fully staged

  // ---- stage 1: U = M * Wb^T for cols [16w,16w+16); packed results stay in regs ----
  u16x4 ur[8];   // statically indexed (full unroll) -> stays in VGPRs
  #pragma unroll
  for (int m = 0; m < 8; ++m) {
    f32x4 acc = {0.f, 0.f, 0.f, 0.f};
    const unsigned short* mr = &Mlds[(m * 16 + l16) * LDW + quad * 8];
    #pragma unroll
    for (int kk = 0; kk < 4; ++kk) {
      u32x4 ua = *(const u32x4*)(mr + kk * 32);
      acc = __builtin_amdgcn_mfma_f32_16x16x32_bf16(
              __builtin_bit_cast(bf16x8, ua), wbf[kk], acc, 0, 0, 0);
    }
    // acc[i] = U[m*16 + quad*4 + i][16w + l16]
    u16x4 h;
    h[0] = f2b(acc[0]); h[1] = f2b(acc[1]); h[2] = f2b(acc[2]); h[3] = f2b(acc[3]);
    ur[m] = h;
  }

  __syncthreads();   // barrier 2: all waves done READING M; safe to overwrite in place

  // ---- write U^T stripe into the SAME buffer (8B writes) ----
  #pragma unroll
  for (int m = 0; m < 8; ++m)
    *(u16x4*)&Mlds[(w * 16 + l16) * LDW + m * 16 + quad * 4] = ur[m];
  // No barrier: wave w reads back only U^T rows [16w,16w+16) which it wrote itself.

  // ---- hoist U^T A-fragments (invariant over output-tile loop) ----
  bf16x8 uf[4];
  {
    const unsigned short* utr = &Mlds[(w * 16 + l16) * LDW + quad * 8];
    #pragma unroll
    for (int kk = 0; kk < 4; ++kk)
      uf[kk] = __builtin_bit_cast(bf16x8, *(const u32x4*)(utr + kk * 32));
  }

  // ---- stage 2: D_mp = U^T x Wa^T -> Y[r][c], fused bias, f32x4 stores ----
  float* orow = out + (size_t)blockIdx.x * 16384;
  const unsigned short* wafl = waf + lane * 8;     // this lane's chunk inside each fragment
  #pragma unroll
  for (int mp = 0; mp < 8; ++mp) {
    f32x4 acc = {0.f, 0.f, 0.f, 0.f};
    #pragma unroll
    for (int kk = 0; kk < 4; ++kk) {
      u32x4 ub = *(const u32x4*)(wafl + (mp * 4 + kk) * 512);   // contiguous 1KB wave-load
      acc = __builtin_amdgcn_mfma_f32_16x16x32_bf16(
              uf[kk], __builtin_bit_cast(bf16x8, ub), acc, 0, 0, 0);
    }
    // D[mm][nn]: nn=l16 -> Y row r = mp*16+l16; mm=quad*4+i -> Y col c = w*16+quad*4+i
    int r  = mp * 16 + l16;
    int c0 = w * 16 + quad * 4;
    f32x4 b = *(const f32x4*)(bias + r * 128 + c0);
    f32x4 y = acc + b;
    *(f32x4*)(orow + r * 128 + c0) = y;            // 16B store, row-contiguous across quads
  }
}

extern "C" void kernel_launch(void* const* d_in, const int* in_sizes, int n_in,
                              void* d_out, int out_size, void* d_ws, size_t ws_size,
                              hipStream_t stream) {
  const float* x  = (const float*)d_in[0];
  const float* wa = (const float*)d_in[1];
  const float* wb = (const float*)d_in[2];
  const float* bs = (const float*)d_in[3];
  float* out = (float*)d_out;

  unsigned short* wsa = (unsigned short*)d_ws;      // 32 KB bf16 Wa (fragment order)
  unsigned short* wsb = wsa + 128 * 128;            // 32 KB bf16 Wb (row-major)

  int N = in_sizes[0] / 16384;                      // 4096

  prep_weights<<<128, 256, 0, stream>>>(wa, wb, wsa, wsb);
  krone_kernel<<<N, 512, 0, stream>>>(x, wsa, wsb, bs, out);
}